// Round 7
// baseline (367.726 us; speedup 1.0000x reference)
//
#include <hip/hip_runtime.h>
#include <hip/hip_bf16.h>
#include <cmath>
#include <cstring>

#define B_SZ   512
#define SLEN   1000
#define DD     16
#define HID    256
#define WIN    64
#define PAIRS  120
#define LSIG   136
#define NWIN   20
#define MAXST  21      // state slots per batch row (0..20)
#define K1P    416     // layer-1 K padded to x32

using short8 = __attribute__((ext_vector_type(8))) short;
using half8  = __attribute__((ext_vector_type(8))) _Float16;
using f32x4  = __attribute__((ext_vector_type(4))) float;

struct SchedArgs { short snapk[SLEN - 1]; };
struct CombArgs  { unsigned char winofm[WIN]; unsigned char zl[WIN]; };
struct ChainArgs { int nsteps; unsigned char kU[32]; };
struct FuseArgs  { unsigned char sidx[WIN]; };

__device__ __forceinline__ unsigned short f2bf(float x) {
  __hip_bfloat16 h = __float2bfloat16(x);
  return *(unsigned short*)&h;
}
__device__ __forceinline__ unsigned short f2h(float x) {
  _Float16 h = (_Float16)x;
  return __builtin_bit_cast(unsigned short, h);
}

// ---------------------------------------------------------------- weights convert
// plain bf16 (fused): W1b [256][416] (pad cols 392..=0), W2b/W3b/Wlb [256][256]
// frag fp16 (chain):  Wxf[(kk*16 + nsub)*64 + lane][8], value = W[nsub*16+(lane&15)][kk*32+(lane>>4)*8+j]
__global__ void wbf_kernel(const float* __restrict__ W1, const float* __restrict__ W2,
                           const float* __restrict__ W3, const float* __restrict__ Wl,
                           unsigned short* __restrict__ W1b, unsigned short* __restrict__ W2b,
                           unsigned short* __restrict__ W3b, unsigned short* __restrict__ Wlb,
                           unsigned short* __restrict__ W1f, unsigned short* __restrict__ W2f,
                           unsigned short* __restrict__ W3f) {
  int idx = blockIdx.x * 256 + threadIdx.x;
  if (idx < HID * K1P) {
    int r = idx / K1P, c = idx - r * K1P;
    float v = (c < HID + LSIG) ? W1[(size_t)r * (HID + LSIG) + c] : 0.f;
    W1b[idx] = f2bf(v);
    return;
  }
  int j0 = idx - HID * K1P;
  if (j0 < 3 * HID * HID) {
    int which = j0 / (HID * HID), o = j0 - which * (HID * HID);
    const float* src = which == 0 ? W2 : which == 1 ? W3 : Wl;
    unsigned short* dst = which == 0 ? W2b : which == 1 ? W3b : Wlb;
    dst[o] = f2bf(src[o]);
    return;
  }
  int f1 = j0 - 3 * HID * HID;
  if (f1 < 13 * 16 * 64 * 8) {                       // W1f (fp16)
    int f = f1;
    int j = f & 7, l15 = (f >> 3) & 15, lq = (f >> 7) & 3, nsub = (f >> 9) & 15, kk = f >> 13;
    int row = nsub * 16 + l15, col = kk * 32 + lq * 8 + j;
    float v = (col < HID + LSIG) ? W1[(size_t)row * (HID + LSIG) + col] : 0.f;
    W1f[f] = f2h(v);
    return;
  }
  int f2 = f1 - 13 * 16 * 64 * 8;
  if (f2 < 2 * 8 * 16 * 64 * 8) {                    // W2f / W3f (fp16)
    int which = f2 >> 16, f = f2 & 65535;
    int j = f & 7, l15 = (f >> 3) & 15, lq = (f >> 7) & 3, nsub = (f >> 9) & 15, kk = (f >> 13) & 7;
    int row = nsub * 16 + l15, col = kk * 32 + lq * 8 + j;
    const float* src = which == 0 ? W2 : W3;
    unsigned short* dst = which == 0 ? W2f : W3f;
    dst[f] = f2h(src[(size_t)row * HID + col]);
  }
}

// ---------------------------------------------------------------- per-window scan (dtsqrt inlined)
__global__ __launch_bounds__(128) void win_kernel(
    const float* __restrict__ z, float* __restrict__ logsig,
    float* __restrict__ dxwin, SchedArgs A)
{
  const int w = blockIdx.x, b = blockIdx.y, tid = threadIdx.x;
  __shared__ float zs[50][16];
  const int ns = (w == NWIN - 1) ? 49 : 50;
  const float* src = z + ((size_t)b * SLEN + 50 * w + 1) * DD;
  const double s999 = 1.0 / (double)(SLEN - 1);
  for (int c = tid; c < ns * 4; c += 128) {
    float4 v = ((const float4*)src)[c];
    int t = 50 * w + (c >> 2);
    double a = (t + 1 == SLEN - 1) ? 1.0 : (double)(t + 1) * s999;
    float s = sqrtf((float)(a - (double)t * s999));
    v.x *= s; v.y *= s; v.z *= s; v.w *= s;
    ((float4*)&zs[0][0])[c] = v;
  }
  int pi = 0, pj = 0;
  if (tid < PAIRS) { int rem = tid, i = 0; while (rem >= DD - 1 - i) { rem -= DD - 1 - i; ++i; } pi = i; pj = i + 1 + rem; }
  __syncthreads();
  float Yi = 0.f, Yj = 0.f, LL = 0.f, Yd = 0.f;
  const int base_t = 50 * w;
  for (int u = 0; u < ns; ++u) {
    const float di = zs[u][pi], dj = zs[u][pj];
    LL = fmaf(Yi, dj, LL); LL = fmaf(-Yj, di, LL);
    Yi += di; Yj += dj;
    if (tid < DD) Yd += zs[u][tid];
    const int m = A.snapk[base_t + u];
    if (m) {
      float* dst = logsig + ((size_t)b * WIN + m) * LSIG;
      if (tid < DD)    dst[tid]      = Yd;
      if (tid < PAIRS) dst[DD + tid] = LL;
    }
  }
  if (tid < DD) dxwin[((size_t)b * NWIN + w) * DD + tid] = Yd;
}

// ---------------------------------------------------------------- combine windows (fully parallel)
// block (m, b): lvl1 += Xs[w], levy = zl ? 0 : 0.5*(LL + Xs_i*Y_j - Xs_j*Y_i)
__global__ __launch_bounds__(128) void comb_kernel(
    float* __restrict__ logsig, const float* __restrict__ dxwin, CombArgs A)
{
  const int m = blockIdx.x, b = blockIdx.y, tid = threadIdx.x;
  float* row = logsig + ((size_t)b * WIN + m) * LSIG;
  if (m == 0) {                         // row 0 of seq is zeros
    if (tid < LSIG) row[tid] = 0.f;
    if (tid + 128 < LSIG) row[tid + 128] = 0.f;
    return;
  }
  __shared__ float Xs[DD], Yt[DD];
  const int w = A.winofm[m];
  if (tid < DD) {
    float acc = 0.f;
    for (int ww = 0; ww < w; ++ww) acc += dxwin[((size_t)b * NWIN + ww) * DD + tid];
    float y = row[tid];
    Xs[tid] = acc; Yt[tid] = y;
    row[tid] = acc + y;                 // lvl1 = X at snapshot
  }
  __syncthreads();
  if (tid < PAIRS) {
    int rem = tid, i = 0; while (rem >= DD - 1 - i) { rem -= DD - 1 - i; ++i; }
    const int pi = i, pj = i + 1 + rem;
    float ll = row[DD + tid];
    row[DD + tid] = A.zl[m] ? 0.f : 0.5f * (ll + Xs[pi] * Yt[pj] - Xs[pj] * Yt[pi]);
  }
}

// ---------------------------------------------------------------- sequential state chain (fp16 MFMA, fp32 accum)
// 32 blocks x 512 threads (8 waves, 1 block/CU). M=16 batch rows/block; wave w
// owns cols [32w,32w+32). Register-resident B-frags: W1 state-part (64 VGPR) +
// W2 + W3 (128 VGPR). W1 logsig-part in LDS (loaded once, 80KB). Activations in
// chunk-of-8 LDS layout: addr(m,k) = ((k>>3)*16+m)*8+(k&7) -> frag reads are
// 64-lane-contiguous ds_read_b128 (zero bank conflicts). Logsig for step m+1
// prefetched into registers during step m. 3 barriers/step.
__global__ __launch_bounds__(512, 2) void chain_kernel(
    const float* __restrict__ logsig,
    const unsigned short* __restrict__ W1f, const unsigned short* __restrict__ W2f,
    const unsigned short* __restrict__ W3f,
    const float* __restrict__ b1, const float* __restrict__ b2, const float* __restrict__ b3,
    unsigned short* __restrict__ statesb, ChainArgs A)
{
  __shared__ __align__(16) unsigned short A0s[52 * 16 * 8];   // 13.3 KB (state+logsig+pad)
  __shared__ __align__(16) unsigned short A1s[32 * 16 * 8];   // 8 KB
  __shared__ __align__(16) unsigned short A2s[32 * 16 * 8];   // 8 KB
  __shared__ __align__(16) unsigned short W1L[80 * 64 * 8];   // 80 KB: [w][nt][kk8][lane][8]
  const int tid = threadIdx.x, g = blockIdx.x;
  const int lane = tid & 63, w = tid >> 6;
  const int l15 = lane & 15, lq = lane >> 4;

  for (int c = tid; c < 52 * 16 * 8; c += 512) A0s[c] = 0;    // state-0 = 0, pad = 0
  for (int c = tid; c < 16 * HID; c += 512) {                 // export state 0 = zeros
    int r = c >> 8, col = c & 255;
    statesb[((size_t)(g * 16 + r) * MAXST + 0) * HID + col] = 0;
  }
  // W1 logsig-part (kk 8..12) -> LDS, cooperative
  for (int it = tid; it < 80 * 64; it += 512) {
    int slot = it >> 6, ln = it & 63;
    int wv = slot / 10, rem = slot - wv * 10, nt = rem / 5, kk8 = rem - nt * 5;
    *(short8*)&W1L[(size_t)it * 8] =
        *(const short8*)(W1f + ((size_t)((kk8 + 8) * 16 + (wv * 2 + nt)) * 64 + ln) * 8);
  }
  // register weights
  half8 w1s[2][8], w2r[2][8], w3r[2][8];
#pragma unroll
  for (int nt = 0; nt < 2; ++nt)
#pragma unroll
    for (int kk = 0; kk < 8; ++kk) {
      w1s[nt][kk] = *(const half8*)(W1f + ((size_t)(kk * 16 + (w * 2 + nt)) * 64 + lane) * 8);
      w2r[nt][kk] = *(const half8*)(W2f + ((size_t)(kk * 16 + (w * 2 + nt)) * 64 + lane) * 8);
      w3r[nt][kk] = *(const half8*)(W3f + ((size_t)(kk * 16 + (w * 2 + nt)) * 64 + lane) * 8);
    }
  float bias1[2], bias2[2], bias3[2];
#pragma unroll
  for (int nt = 0; nt < 2; ++nt) {
    int col = (w * 2 + nt) * 16 + l15;
    bias1[nt] = b1[col]; bias2[nt] = b2[col]; bias3[nt] = b3[col];
  }
  // logsig prefetch plumbing: thread covers elements c = tid + 512*i of 16*LSIG
  size_t gbase[5]; int a0off[5]; int nld = 0;
#pragma unroll
  for (int i = 0; i < 5; ++i) {
    int c = tid + 512 * i;
    if (c < 16 * LSIG) {
      int r = c / LSIG, cc = c - r * LSIG;
      gbase[i] = ((size_t)(g * 16 + r) * WIN) * LSIG + cc;
      a0off[i] = (((HID + cc) >> 3) * 16 + r) * 8 + ((HID + cc) & 7);
      nld = i + 1;
    }
  }
  float lsr[5];
  {
    const int k0 = A.kU[0];
    for (int i = 0; i < nld; ++i) lsr[i] = logsig[gbase[i] + (size_t)k0 * LSIG];
  }
  __syncthreads();

  for (int m = 0; m < A.nsteps; ++m) {
    // stage logsig (prefetched regs) -> A0 chunk-8 cols 256..391
    for (int i = 0; i < nld; ++i) A0s[a0off[i]] = f2h(lsr[i]);
    __syncthreads();
    if (m + 1 < A.nsteps) {                         // prefetch next step
      const int kn = A.kU[m + 1];
      for (int i = 0; i < nld; ++i) lsr[i] = logsig[gbase[i] + (size_t)kn * LSIG];
    }
    // ---- L1: K=416 (8 reg kk + 5 LDS kk), split parity accumulators
    {
      f32x4 acc[2][2] = {{{0.f,0.f,0.f,0.f},{0.f,0.f,0.f,0.f}},{{0.f,0.f,0.f,0.f},{0.f,0.f,0.f,0.f}}};
#pragma unroll
      for (int kk = 0; kk < 8; ++kk) {
        half8 af = *(const half8*)&A0s[((kk * 4 + lq) * 16 + l15) * 8];
        acc[kk & 1][0] = __builtin_amdgcn_mfma_f32_16x16x32_f16(af, w1s[0][kk], acc[kk & 1][0], 0, 0, 0);
        acc[kk & 1][1] = __builtin_amdgcn_mfma_f32_16x16x32_f16(af, w1s[1][kk], acc[kk & 1][1], 0, 0, 0);
      }
#pragma unroll
      for (int kk = 8; kk < 13; ++kk) {
        half8 af = *(const half8*)&A0s[((kk * 4 + lq) * 16 + l15) * 8];
        half8 bf0 = *(const half8*)&W1L[(((w * 10) + 0 + (kk - 8)) * 64 + lane) * 8];
        half8 bf1 = *(const half8*)&W1L[(((w * 10) + 5 + (kk - 8)) * 64 + lane) * 8];
        acc[kk & 1][0] = __builtin_amdgcn_mfma_f32_16x16x32_f16(af, bf0, acc[kk & 1][0], 0, 0, 0);
        acc[kk & 1][1] = __builtin_amdgcn_mfma_f32_16x16x32_f16(af, bf1, acc[kk & 1][1], 0, 0, 0);
      }
#pragma unroll
      for (int nt = 0; nt < 2; ++nt) {
        f32x4 s = acc[0][nt] + acc[1][nt];
        int col = w * 32 + nt * 16 + l15;
        int base = ((col >> 3) * 16) * 8 + (col & 7);
#pragma unroll
        for (int r4 = 0; r4 < 4; ++r4)
          A1s[base + (lq * 4 + r4) * 8] = f2h(fmaxf(s[r4] + bias1[nt], 0.f));
      }
    }
    __syncthreads();
    // ---- L2: K=256, weights in registers
    {
      f32x4 acc[2][2] = {{{0.f,0.f,0.f,0.f},{0.f,0.f,0.f,0.f}},{{0.f,0.f,0.f,0.f},{0.f,0.f,0.f,0.f}}};
#pragma unroll
      for (int kk = 0; kk < 8; ++kk) {
        half8 af = *(const half8*)&A1s[((kk * 4 + lq) * 16 + l15) * 8];
        acc[kk & 1][0] = __builtin_amdgcn_mfma_f32_16x16x32_f16(af, w2r[0][kk], acc[kk & 1][0], 0, 0, 0);
        acc[kk & 1][1] = __builtin_amdgcn_mfma_f32_16x16x32_f16(af, w2r[1][kk], acc[kk & 1][1], 0, 0, 0);
      }
#pragma unroll
      for (int nt = 0; nt < 2; ++nt) {
        f32x4 s = acc[0][nt] + acc[1][nt];
        int col = w * 32 + nt * 16 + l15;
        int base = ((col >> 3) * 16) * 8 + (col & 7);
#pragma unroll
        for (int r4 = 0; r4 < 4; ++r4)
          A2s[base + (lq * 4 + r4) * 8] = f2h(fmaxf(s[r4] + bias2[nt], 0.f));
      }
    }
    __syncthreads();
    // ---- L3: K=256, regs; tanh -> A0 state + export bf16 (no barrier: next
    //      stage writes disjoint logsig cols; barrier after stage covers both)
    {
      f32x4 acc[2][2] = {{{0.f,0.f,0.f,0.f},{0.f,0.f,0.f,0.f}},{{0.f,0.f,0.f,0.f},{0.f,0.f,0.f,0.f}}};
#pragma unroll
      for (int kk = 0; kk < 8; ++kk) {
        half8 af = *(const half8*)&A2s[((kk * 4 + lq) * 16 + l15) * 8];
        acc[kk & 1][0] = __builtin_amdgcn_mfma_f32_16x16x32_f16(af, w3r[0][kk], acc[kk & 1][0], 0, 0, 0);
        acc[kk & 1][1] = __builtin_amdgcn_mfma_f32_16x16x32_f16(af, w3r[1][kk], acc[kk & 1][1], 0, 0, 0);
      }
#pragma unroll
      for (int nt = 0; nt < 2; ++nt) {
        f32x4 s = acc[0][nt] + acc[1][nt];
        int col = w * 32 + nt * 16 + l15;
        int base = ((col >> 3) * 16) * 8 + (col & 7);
#pragma unroll
        for (int r4 = 0; r4 < 4; ++r4) {
          int row = lq * 4 + r4;
          float tv = tanhf(s[r4] + bias3[nt]);
          A0s[base + row * 8] = f2h(tv);
          statesb[((size_t)(g * 16 + row) * MAXST + (m + 1)) * HID + col] = f2bf(tv);
        }
      }
    }
    __syncthreads();
  }
}

// ---------------------------------------------------------------- fused batched MLP (bf16 MFMA)
template <int EPI>  // 0 relu->LDS, 1 tanh->LDS, 2 none->global fp32
__device__ __forceinline__ void layer_234(
    const unsigned short* __restrict__ inb, unsigned short* __restrict__ outb,
    const unsigned short* __restrict__ Wb, const float* __restrict__ bias,
    float* __restrict__ outg, int band, unsigned short* __restrict__ wtile,
    int tid, int wm, int wn, int l15, int lq)
{
  for (int nh = 0; nh < 2; ++nh) {
    f32x4 acc[4][4];
#pragma unroll
    for (int a = 0; a < 4; ++a)
#pragma unroll
      for (int t = 0; t < 4; ++t) acc[a][t] = (f32x4){0.f, 0.f, 0.f, 0.f};
    for (int kk = 0; kk < HID; kk += 32) {
#pragma unroll
      for (int i = 0; i < 2; ++i) {
        int c = tid + 256 * i; int n = c >> 2, cc = (c & 3) * 8;
        short8 wv = *(const short8*)(Wb + ((size_t)(nh * 128 + n)) * HID + kk + cc);
        *(short8*)&wtile[n * 40 + cc] = wv;
      }
      __syncthreads();
      short8 af[4], bfr[4];
#pragma unroll
      for (int a = 0; a < 4; ++a) af[a]  = *(const short8*)&inb[(wm * 64 + a * 16 + l15) * 264 + kk + lq * 8];
#pragma unroll
      for (int t = 0; t < 4; ++t) bfr[t] = *(const short8*)&wtile[(wn * 64 + t * 16 + l15) * 40 + lq * 8];
#pragma unroll
      for (int a = 0; a < 4; ++a)
#pragma unroll
        for (int t = 0; t < 4; ++t)
          acc[a][t] = __builtin_amdgcn_mfma_f32_16x16x32_bf16(af[a], bfr[t], acc[a][t], 0, 0, 0);
      __syncthreads();
    }
#pragma unroll
    for (int t = 0; t < 4; ++t) {
      int col = nh * 128 + wn * 64 + t * 16 + l15;
      float bv = (EPI < 2) ? bias[col] : 0.f;
#pragma unroll
      for (int a = 0; a < 4; ++a)
#pragma unroll
        for (int r4 = 0; r4 < 4; ++r4) {
          int row = wm * 64 + a * 16 + lq * 4 + r4;
          float v = acc[a][t][r4] + bv;
          if (EPI == 0) { outb[row * 264 + col] = f2bf(fmaxf(v, 0.f)); }
          else if (EPI == 1) { outb[row * 264 + col] = f2bf(tanhf(v)); }
          else { outg[((size_t)(band * 128 + row)) * HID + col] = v; }
        }
    }
  }
  __syncthreads();
}

__global__ __launch_bounds__(256, 1) void fused_kernel(
    const unsigned short* __restrict__ statesb, const float* __restrict__ logsig,
    const unsigned short* __restrict__ W1b, const unsigned short* __restrict__ W2b,
    const unsigned short* __restrict__ W3b, const unsigned short* __restrict__ Wlb,
    const float* __restrict__ b1, const float* __restrict__ b2, const float* __restrict__ b3,
    float* __restrict__ out, FuseArgs F)
{
  __shared__ __align__(16) unsigned short act1[128 * 264];
  __shared__ __align__(16) unsigned short act2[128 * 264];
  __shared__ __align__(16) unsigned short atile[128 * 40];
  __shared__ __align__(16) unsigned short wtile[128 * 40];
  const int tid = threadIdx.x, band = blockIdx.x;
  const int lane = tid & 63, wave = tid >> 6;
  const int wm = wave & 1, wn = wave >> 1;
  const int l15 = lane & 15, lq = lane >> 4;

  for (int nh = 0; nh < 2; ++nh) {
    f32x4 acc[4][4];
#pragma unroll
    for (int a = 0; a < 4; ++a)
#pragma unroll
      for (int t = 0; t < 4; ++t) acc[a][t] = (f32x4){0.f, 0.f, 0.f, 0.f};
    for (int kk = 0; kk < K1P; kk += 32) {
#pragma unroll
      for (int i = 0; i < 2; ++i) {        // stage A-tile 128x32
        int c = tid + 256 * i;
        int r = c >> 2, cc = (c & 3) * 8;
        int col = kk + cc;
        int bA = band * 2 + (r >> 6), ks = r & 63;
        short8 pk;
        if (col < HID) {
          pk = *(const short8*)(statesb + ((size_t)bA * MAXST + F.sidx[ks]) * HID + col);
        } else {
          const float* sp = logsig + ((size_t)bA * WIN + ks) * LSIG + (col - HID);
          float4 v0 = ((const float4*)sp)[0];
          float4 v1 = ((const float4*)sp)[1];
          pk[0] = (short)f2bf(v0.x); pk[1] = (short)f2bf(v0.y); pk[2] = (short)f2bf(v0.z); pk[3] = (short)f2bf(v0.w);
          pk[4] = (short)f2bf(v1.x); pk[5] = (short)f2bf(v1.y); pk[6] = (short)f2bf(v1.z); pk[7] = (short)f2bf(v1.w);
        }
        *(short8*)&atile[r * 40 + cc] = pk;
      }
#pragma unroll
      for (int i = 0; i < 2; ++i) {        // stage W-tile 128x32
        int c = tid + 256 * i; int n = c >> 2, cc = (c & 3) * 8;
        short8 wv = *(const short8*)(W1b + ((size_t)(nh * 128 + n)) * K1P + kk + cc);
        *(short8*)&wtile[n * 40 + cc] = wv;
      }
      __syncthreads();
      short8 af[4], bfr[4];
#pragma unroll
      for (int a = 0; a < 4; ++a) af[a]  = *(const short8*)&atile[(wm * 64 + a * 16 + l15) * 40 + lq * 8];
#pragma unroll
      for (int t = 0; t < 4; ++t) bfr[t] = *(const short8*)&wtile[(wn * 64 + t * 16 + l15) * 40 + lq * 8];
#pragma unroll
      for (int a = 0; a < 4; ++a)
#pragma unroll
        for (int t = 0; t < 4; ++t)
          acc[a][t] = __builtin_amdgcn_mfma_f32_16x16x32_bf16(af[a], bfr[t], acc[a][t], 0, 0, 0);
      __syncthreads();
    }
#pragma unroll
    for (int t = 0; t < 4; ++t) {
      int col = nh * 128 + wn * 64 + t * 16 + l15;
      float bv = b1[col];
#pragma unroll
      for (int a = 0; a < 4; ++a)
#pragma unroll
        for (int r4 = 0; r4 < 4; ++r4) {
          int row = wm * 64 + a * 16 + lq * 4 + r4;
          act1[row * 264 + col] = f2bf(fmaxf(acc[a][t][r4] + bv, 0.f));
        }
    }
  }
  __syncthreads();

  layer_234<0>(act1, act2, W2b, b2, nullptr, band, wtile, tid, wm, wn, l15, lq);
  layer_234<1>(act2, act1, W3b, b3, nullptr, band, wtile, tid, wm, wn, l15, lq);
  layer_234<2>(act1, nullptr, Wlb, nullptr, out, band, wtile, tid, wm, wn, l15, lq);
}

// ---------------------------------------------------------------- host schedule
static void build_sched(SchedArgs& P, CombArgs& CB, ChainArgs& CH, FuseArgs& FU) {
  double tb[SLEN], tt[WIN], tu[NWIN];
  const double s999 = 1.0 / (double)(SLEN - 1);
  const double s63  = 1.0 / (double)(WIN - 1);
  for (int i = 0; i < SLEN; ++i) tb[i] = (double)i * s999;
  tb[SLEN - 1] = 1.0;
  for (int k = 0; k < WIN; ++k) tt[k] = (double)k * s63;
  tt[WIN - 1] = 1.0;
  for (int j = 0; j < NWIN; ++j) tu[j] = tb[50 * j];

  int t_idx[WIN - 1], u_for_t[WIN - 1];
  for (int k = 1; k < WIN; ++k) {
    int ii = 0;
    for (int q = 0; q < SLEN; ++q) if (tb[q] <= tt[k]) ii = q;
    t_idx[k - 1] = ii;
    int jj = 0;
    for (int q = 0; q < NWIN; ++q) if (tu[q] <= tt[k]) jj = q;
    u_for_t[k - 1] = jj;
  }
  for (int t = 0; t < SLEN - 1; ++t) P.snapk[t] = 0;
  for (int m = 1; m < WIN; ++m) P.snapk[t_idx[m - 1] - 1] = (short)m;

  for (int m = 0; m < WIN; ++m) { CB.winofm[m] = 0; CB.zl[m] = 0; }
  for (int m = 1; m < WIN; ++m) {
    int p = t_idx[m - 1];
    CB.winofm[m] = (unsigned char)((p - 1) / 50);
    CB.zl[m] = (p % 50 == 0) ? 1 : 0;
  }

  double qt[32]; int nq = 0, last = -1;
  for (int m = 0; m < WIN - 1; ++m) {
    const int iu = u_for_t[m];
    if (iu != last) { qt[nq++] = tu[iu]; last = iu; }
  }
  qt[nq++] = tt[WIN - 1];
  int upd[WIN]; int qh = 0;
  for (int i = 0; i < WIN; ++i) {
    upd[i] = 0;
    if (qh < nq && tt[i] >= qt[qh]) { qh++; upd[i] = 1; }
  }
  int nU = 0;
  for (int k = 0; k < WIN; ++k) if (upd[k]) { if (nU < 32) CH.kU[nU] = (unsigned char)k; ++nU; }
  int cnt = 0;
  for (int k = 0; k < WIN; ++k) { FU.sidx[k] = (unsigned char)cnt; if (upd[k]) ++cnt; }
  CH.nsteps = FU.sidx[WIN - 1];
}

extern "C" void kernel_launch(void* const* d_in, const int* in_sizes, int n_in,
                              void* d_out, int out_size, void* d_ws, size_t ws_size,
                              hipStream_t stream) {
  const float* z  = (const float*)d_in[0];
  const float* W1 = (const float*)d_in[1];
  const float* b1 = (const float*)d_in[2];
  const float* W2 = (const float*)d_in[3];
  const float* b2 = (const float*)d_in[4];
  const float* W3 = (const float*)d_in[5];
  const float* b3 = (const float*)d_in[6];
  const float* Wl = (const float*)d_in[7];

  char* ws = (char*)d_ws;
  float* logsig = (float*)(ws);                                         // 17.83 MB
  size_t o = (size_t)B_SZ * WIN * LSIG * 4;
  float* dxwin            = (float*)(ws + o); o += (size_t)B_SZ * NWIN * DD * 4;
  unsigned short* statesb = (unsigned short*)(ws + o); o += (size_t)B_SZ * MAXST * HID * 2;
  unsigned short* W1b     = (unsigned short*)(ws + o); o += (size_t)HID * K1P * 2;
  unsigned short* W2b     = (unsigned short*)(ws + o); o += (size_t)HID * HID * 2;
  unsigned short* W3b     = (unsigned short*)(ws + o); o += (size_t)HID * HID * 2;
  unsigned short* Wlb     = (unsigned short*)(ws + o); o += (size_t)HID * HID * 2;
  unsigned short* W1f     = (unsigned short*)(ws + o); o += (size_t)13 * 16 * 64 * 8 * 2;
  unsigned short* W2f     = (unsigned short*)(ws + o); o += (size_t)8 * 16 * 64 * 8 * 2;
  unsigned short* W3f     = (unsigned short*)(ws + o); o += (size_t)8 * 16 * 64 * 8 * 2;

  SchedArgs P; CombArgs CB; ChainArgs CH; FuseArgs FU;
  build_sched(P, CB, CH, FU);

  const int wbf_total = HID * K1P + 3 * HID * HID + 13 * 16 * 64 * 8 + 2 * 8 * 16 * 64 * 8;
  wbf_kernel<<<(wbf_total + 255) / 256, 256, 0, stream>>>(
      W1, W2, W3, Wl, W1b, W2b, W3b, Wlb, W1f, W2f, W3f);
  win_kernel<<<dim3(NWIN, B_SZ), 128, 0, stream>>>(z, logsig, dxwin, P);
  comb_kernel<<<dim3(WIN, B_SZ), 128, 0, stream>>>(logsig, dxwin, CB);
  chain_kernel<<<32, 512, 0, stream>>>(logsig, W1f, W2f, W3f, b1, b2, b3, statesb, CH);
  fused_kernel<<<256, 256, 0, stream>>>(statesb, logsig, W1b, W2b, W3b, Wlb,
                                        b1, b2, b3, (float*)d_out, FU);
}

// Round 8
// 352.547 us; speedup vs baseline: 1.0431x; 1.0431x over previous
//
#include <hip/hip_runtime.h>
#include <hip/hip_bf16.h>
#include <cmath>
#include <cstring>

#define B_SZ   512
#define SLEN   1000
#define DD     16
#define HID    256
#define WIN    64
#define PAIRS  120
#define LSIG   136
#define NWIN   20
#define MAXST  21      // state slots per batch row (0..20)
#define K1P    416     // layer-1 K padded to x32

using short8 = __attribute__((ext_vector_type(8))) short;
using half8  = __attribute__((ext_vector_type(8))) _Float16;
using f32x4  = __attribute__((ext_vector_type(4))) float;

struct SchedArgs { short snapk[SLEN - 1]; };
struct CombArgs  { unsigned char winofm[WIN]; unsigned char zl[WIN]; };
struct ChainArgs { int nsteps; unsigned char kU[32]; };
struct FuseArgs  { unsigned char sidx[WIN]; };

__device__ __forceinline__ unsigned short f2bf(float x) {
  __hip_bfloat16 h = __float2bfloat16(x);
  return *(unsigned short*)&h;
}
__device__ __forceinline__ unsigned short f2h(float x) {
  _Float16 h = (_Float16)x;
  return __builtin_bit_cast(unsigned short, h);
}

// ---------------------------------------------------------------- weights convert
// plain bf16 (fused): W1b [256][416] (pad cols 392..=0), W2b/W3b/Wlb [256][256]
// frag fp16 (chain):  Wxf[(kk*16 + nsub)*64 + lane][8], value = W[nsub*16+(lane&15)][kk*32+(lane>>4)*8+j]
__global__ void wbf_kernel(const float* __restrict__ W1, const float* __restrict__ W2,
                           const float* __restrict__ W3, const float* __restrict__ Wl,
                           unsigned short* __restrict__ W1b, unsigned short* __restrict__ W2b,
                           unsigned short* __restrict__ W3b, unsigned short* __restrict__ Wlb,
                           unsigned short* __restrict__ W1f, unsigned short* __restrict__ W2f,
                           unsigned short* __restrict__ W3f) {
  int idx = blockIdx.x * 256 + threadIdx.x;
  if (idx < HID * K1P) {
    int r = idx / K1P, c = idx - r * K1P;
    float v = (c < HID + LSIG) ? W1[(size_t)r * (HID + LSIG) + c] : 0.f;
    W1b[idx] = f2bf(v);
    return;
  }
  int j0 = idx - HID * K1P;
  if (j0 < 3 * HID * HID) {
    int which = j0 / (HID * HID), o = j0 - which * (HID * HID);
    const float* src = which == 0 ? W2 : which == 1 ? W3 : Wl;
    unsigned short* dst = which == 0 ? W2b : which == 1 ? W3b : Wlb;
    dst[o] = f2bf(src[o]);
    return;
  }
  int f1 = j0 - 3 * HID * HID;
  if (f1 < 13 * 16 * 64 * 8) {                       // W1f (fp16)
    int f = f1;
    int j = f & 7, l15 = (f >> 3) & 15, lq = (f >> 7) & 3, nsub = (f >> 9) & 15, kk = f >> 13;
    int row = nsub * 16 + l15, col = kk * 32 + lq * 8 + j;
    float v = (col < HID + LSIG) ? W1[(size_t)row * (HID + LSIG) + col] : 0.f;
    W1f[f] = f2h(v);
    return;
  }
  int f2 = f1 - 13 * 16 * 64 * 8;
  if (f2 < 2 * 8 * 16 * 64 * 8) {                    // W2f / W3f (fp16)
    int which = f2 >> 16, f = f2 & 65535;
    int j = f & 7, l15 = (f >> 3) & 15, lq = (f >> 7) & 3, nsub = (f >> 9) & 15, kk = (f >> 13) & 7;
    int row = nsub * 16 + l15, col = kk * 32 + lq * 8 + j;
    const float* src = which == 0 ? W2 : W3;
    unsigned short* dst = which == 0 ? W2f : W3f;
    dst[f] = f2h(src[(size_t)row * HID + col]);
  }
}

// ---------------------------------------------------------------- per-window scan (dtsqrt inlined)
__global__ __launch_bounds__(128) void win_kernel(
    const float* __restrict__ z, float* __restrict__ logsig,
    float* __restrict__ dxwin, SchedArgs A)
{
  const int w = blockIdx.x, b = blockIdx.y, tid = threadIdx.x;
  __shared__ float zs[50][16];
  const int ns = (w == NWIN - 1) ? 49 : 50;
  const float* src = z + ((size_t)b * SLEN + 50 * w + 1) * DD;
  const double s999 = 1.0 / (double)(SLEN - 1);
  for (int c = tid; c < ns * 4; c += 128) {
    float4 v = ((const float4*)src)[c];
    int t = 50 * w + (c >> 2);
    double a = (t + 1 == SLEN - 1) ? 1.0 : (double)(t + 1) * s999;
    float s = sqrtf((float)(a - (double)t * s999));
    v.x *= s; v.y *= s; v.z *= s; v.w *= s;
    ((float4*)&zs[0][0])[c] = v;
  }
  int pi = 0, pj = 0;
  if (tid < PAIRS) { int rem = tid, i = 0; while (rem >= DD - 1 - i) { rem -= DD - 1 - i; ++i; } pi = i; pj = i + 1 + rem; }
  __syncthreads();
  float Yi = 0.f, Yj = 0.f, LL = 0.f, Yd = 0.f;
  const int base_t = 50 * w;
  for (int u = 0; u < ns; ++u) {
    const float di = zs[u][pi], dj = zs[u][pj];
    LL = fmaf(Yi, dj, LL); LL = fmaf(-Yj, di, LL);
    Yi += di; Yj += dj;
    if (tid < DD) Yd += zs[u][tid];
    const int m = A.snapk[base_t + u];
    if (m) {
      float* dst = logsig + ((size_t)b * WIN + m) * LSIG;
      if (tid < DD)    dst[tid]      = Yd;
      if (tid < PAIRS) dst[DD + tid] = LL;
    }
  }
  if (tid < DD) dxwin[((size_t)b * NWIN + w) * DD + tid] = Yd;
}

// ---------------------------------------------------------------- combine windows (fully parallel)
__global__ __launch_bounds__(128) void comb_kernel(
    float* __restrict__ logsig, const float* __restrict__ dxwin, CombArgs A)
{
  const int m = blockIdx.x, b = blockIdx.y, tid = threadIdx.x;
  float* row = logsig + ((size_t)b * WIN + m) * LSIG;
  if (m == 0) {                         // row 0 of seq is zeros
    if (tid < LSIG) row[tid] = 0.f;
    if (tid + 128 < LSIG) row[tid + 128] = 0.f;
    return;
  }
  __shared__ float Xs[DD], Yt[DD];
  const int w = A.winofm[m];
  if (tid < DD) {
    float acc = 0.f;
    for (int ww = 0; ww < w; ++ww) acc += dxwin[((size_t)b * NWIN + ww) * DD + tid];
    float y = row[tid];
    Xs[tid] = acc; Yt[tid] = y;
    row[tid] = acc + y;                 // lvl1 = X at snapshot
  }
  __syncthreads();
  if (tid < PAIRS) {
    int rem = tid, i = 0; while (rem >= DD - 1 - i) { rem -= DD - 1 - i; ++i; }
    const int pi = i, pj = i + 1 + rem;
    float ll = row[DD + tid];
    row[DD + tid] = A.zl[m] ? 0.f : 0.5f * (ll + Xs[pi] * Yt[pj] - Xs[pj] * Yt[pi]);
  }
}

// ---------------------------------------------------------------- sequential state chain (fp16 MFMA, fp32 accum)
// 32 blocks x 512 threads (8 waves, 1 block/CU). M=16 batch rows/block; wave w
// owns cols [32w,32w+32). Register-resident B-frags: W1 state-part + W2 + W3
// (~192 VGPR) -- REQUIRES the 256-VGPR budget: __launch_bounds__(512,1).
// (512,2) caps at 128 VGPR -> ~110 regs spill to scratch, reloaded every step:
// R7 measured 146us vs 119us. W1 logsig-part in LDS (80KB, loaded once).
// Activations in chunk-of-8 LDS layout -> frag reads are 64-lane-contiguous
// ds_read_b128 (conflict-free). Next step's logsig prefetched during L1,
// staged into A0s inside the L1->L2 barrier window. 3 barriers/step.
__global__ __launch_bounds__(512, 1) void chain_kernel(
    const float* __restrict__ logsig,
    const unsigned short* __restrict__ W1f, const unsigned short* __restrict__ W2f,
    const unsigned short* __restrict__ W3f,
    const float* __restrict__ b1, const float* __restrict__ b2, const float* __restrict__ b3,
    unsigned short* __restrict__ statesb, ChainArgs A)
{
  __shared__ __align__(16) unsigned short A0s[52 * 16 * 8];   // 13.3 KB (state+logsig+pad)
  __shared__ __align__(16) unsigned short A1s[32 * 16 * 8];   // 8 KB
  __shared__ __align__(16) unsigned short A2s[32 * 16 * 8];   // 8 KB
  __shared__ __align__(16) unsigned short W1L[80 * 64 * 8];   // 80 KB: [w][nt][kk8][lane][8]
  const int tid = threadIdx.x, g = blockIdx.x;
  const int lane = tid & 63, w = tid >> 6;
  const int l15 = lane & 15, lq = lane >> 4;

  for (int c = tid; c < 52 * 16 * 8; c += 512) A0s[c] = 0;    // state-0 = 0, pad = 0
  for (int c = tid; c < 16 * HID; c += 512) {                 // export state 0 = zeros
    int r = c >> 8, col = c & 255;
    statesb[((size_t)(g * 16 + r) * MAXST + 0) * HID + col] = 0;
  }
  // W1 logsig-part (kk 8..12) -> LDS, cooperative
  for (int it = tid; it < 80 * 64; it += 512) {
    int slot = it >> 6, ln = it & 63;
    int wv = slot / 10, rem = slot - wv * 10, nt = rem / 5, kk8 = rem - nt * 5;
    *(short8*)&W1L[(size_t)it * 8] =
        *(const short8*)(W1f + ((size_t)((kk8 + 8) * 16 + (wv * 2 + nt)) * 64 + ln) * 8);
  }
  // register weights
  half8 w1s[2][8], w2r[2][8], w3r[2][8];
#pragma unroll
  for (int nt = 0; nt < 2; ++nt)
#pragma unroll
    for (int kk = 0; kk < 8; ++kk) {
      w1s[nt][kk] = *(const half8*)(W1f + ((size_t)(kk * 16 + (w * 2 + nt)) * 64 + lane) * 8);
      w2r[nt][kk] = *(const half8*)(W2f + ((size_t)(kk * 16 + (w * 2 + nt)) * 64 + lane) * 8);
      w3r[nt][kk] = *(const half8*)(W3f + ((size_t)(kk * 16 + (w * 2 + nt)) * 64 + lane) * 8);
    }
  float bias1[2], bias2[2], bias3[2];
#pragma unroll
  for (int nt = 0; nt < 2; ++nt) {
    int col = (w * 2 + nt) * 16 + l15;
    bias1[nt] = b1[col]; bias2[nt] = b2[col]; bias3[nt] = b3[col];
  }
  // logsig plumbing: thread covers elements c = tid + 512*i of 16*LSIG
  int gofs[5]; int a0off[5]; int nld = 0;
#pragma unroll
  for (int i = 0; i < 5; ++i) {
    int c = tid + 512 * i;
    if (c < 16 * LSIG) {
      int r = c / LSIG, cc = c - r * LSIG;
      gofs[i] = ((g * 16 + r) * WIN) * LSIG + cc;
      a0off[i] = (((HID + cc) >> 3) * 16 + r) * 8 + ((HID + cc) & 7);
      nld = i + 1;
    }
  }
  float lsr[5];
  {
    const int k0 = A.kU[0];
    for (int i = 0; i < nld; ++i) lsr[i] = logsig[gofs[i] + k0 * LSIG];
  }
  __syncthreads();                     // zero-init visible to all
  for (int i = 0; i < nld; ++i) A0s[a0off[i]] = f2h(lsr[i]);   // stage logsig(0)
  __syncthreads();                     // staging + W1L visible

  for (int m = 0; m < A.nsteps; ++m) {
    // issue next step's logsig prefetch (overlaps L1 MFMAs)
    if (m + 1 < A.nsteps) {
      const int kn = A.kU[m + 1];
      for (int i = 0; i < nld; ++i) lsr[i] = logsig[gofs[i] + kn * LSIG];
    }
    // ---- L1: K=416 (8 reg kk + 5 LDS kk), split parity accumulators
    {
      f32x4 acc[2][2] = {{{0.f,0.f,0.f,0.f},{0.f,0.f,0.f,0.f}},{{0.f,0.f,0.f,0.f},{0.f,0.f,0.f,0.f}}};
#pragma unroll
      for (int kk = 0; kk < 8; ++kk) {
        half8 af = *(const half8*)&A0s[((kk * 4 + lq) * 16 + l15) * 8];
        acc[kk & 1][0] = __builtin_amdgcn_mfma_f32_16x16x32_f16(af, w1s[0][kk], acc[kk & 1][0], 0, 0, 0);
        acc[kk & 1][1] = __builtin_amdgcn_mfma_f32_16x16x32_f16(af, w1s[1][kk], acc[kk & 1][1], 0, 0, 0);
      }
#pragma unroll
      for (int kk = 8; kk < 13; ++kk) {
        half8 af = *(const half8*)&A0s[((kk * 4 + lq) * 16 + l15) * 8];
        half8 bf0 = *(const half8*)&W1L[(((w * 10) + 0 + (kk - 8)) * 64 + lane) * 8];
        half8 bf1 = *(const half8*)&W1L[(((w * 10) + 5 + (kk - 8)) * 64 + lane) * 8];
        acc[kk & 1][0] = __builtin_amdgcn_mfma_f32_16x16x32_f16(af, bf0, acc[kk & 1][0], 0, 0, 0);
        acc[kk & 1][1] = __builtin_amdgcn_mfma_f32_16x16x32_f16(af, bf1, acc[kk & 1][1], 0, 0, 0);
      }
#pragma unroll
      for (int nt = 0; nt < 2; ++nt) {
        f32x4 s = acc[0][nt] + acc[1][nt];
        int col = w * 32 + nt * 16 + l15;
        int base = ((col >> 3) * 16) * 8 + (col & 7);
#pragma unroll
        for (int r4 = 0; r4 < 4; ++r4)
          A1s[base + (lq * 4 + r4) * 8] = f2h(fmaxf(s[r4] + bias1[nt], 0.f));
      }
    }
    __syncthreads();
    // stage logsig(m+1) into A0s (region free after L1; visible after barrier 3)
    if (m + 1 < A.nsteps)
      for (int i = 0; i < nld; ++i) A0s[a0off[i]] = f2h(lsr[i]);
    // ---- L2: K=256, weights in registers
    {
      f32x4 acc[2][2] = {{{0.f,0.f,0.f,0.f},{0.f,0.f,0.f,0.f}},{{0.f,0.f,0.f,0.f},{0.f,0.f,0.f,0.f}}};
#pragma unroll
      for (int kk = 0; kk < 8; ++kk) {
        half8 af = *(const half8*)&A1s[((kk * 4 + lq) * 16 + l15) * 8];
        acc[kk & 1][0] = __builtin_amdgcn_mfma_f32_16x16x32_f16(af, w2r[0][kk], acc[kk & 1][0], 0, 0, 0);
        acc[kk & 1][1] = __builtin_amdgcn_mfma_f32_16x16x32_f16(af, w2r[1][kk], acc[kk & 1][1], 0, 0, 0);
      }
#pragma unroll
      for (int nt = 0; nt < 2; ++nt) {
        f32x4 s = acc[0][nt] + acc[1][nt];
        int col = w * 32 + nt * 16 + l15;
        int base = ((col >> 3) * 16) * 8 + (col & 7);
#pragma unroll
        for (int r4 = 0; r4 < 4; ++r4)
          A2s[base + (lq * 4 + r4) * 8] = f2h(fmaxf(s[r4] + bias2[nt], 0.f));
      }
    }
    __syncthreads();
    // ---- L3: K=256, regs; tanh -> A0 state + export bf16
    {
      f32x4 acc[2][2] = {{{0.f,0.f,0.f,0.f},{0.f,0.f,0.f,0.f}},{{0.f,0.f,0.f,0.f},{0.f,0.f,0.f,0.f}}};
#pragma unroll
      for (int kk = 0; kk < 8; ++kk) {
        half8 af = *(const half8*)&A2s[((kk * 4 + lq) * 16 + l15) * 8];
        acc[kk & 1][0] = __builtin_amdgcn_mfma_f32_16x16x32_f16(af, w3r[0][kk], acc[kk & 1][0], 0, 0, 0);
        acc[kk & 1][1] = __builtin_amdgcn_mfma_f32_16x16x32_f16(af, w3r[1][kk], acc[kk & 1][1], 0, 0, 0);
      }
#pragma unroll
      for (int nt = 0; nt < 2; ++nt) {
        f32x4 s = acc[0][nt] + acc[1][nt];
        int col = w * 32 + nt * 16 + l15;
        int base = ((col >> 3) * 16) * 8 + (col & 7);
#pragma unroll
        for (int r4 = 0; r4 < 4; ++r4) {
          int row = lq * 4 + r4;
          float tv = tanhf(s[r4] + bias3[nt]);
          A0s[base + row * 8] = f2h(tv);
          statesb[((size_t)(g * 16 + row) * MAXST + (m + 1)) * HID + col] = f2bf(tv);
        }
      }
    }
    __syncthreads();
  }
}

// ---------------------------------------------------------------- fused batched MLP (bf16 MFMA)
template <int EPI>  // 0 relu->LDS, 1 tanh->LDS, 2 none->global fp32
__device__ __forceinline__ void layer_234(
    const unsigned short* __restrict__ inb, unsigned short* __restrict__ outb,
    const unsigned short* __restrict__ Wb, const float* __restrict__ bias,
    float* __restrict__ outg, int band, unsigned short* __restrict__ wtile,
    int tid, int wm, int wn, int l15, int lq)
{
  for (int nh = 0; nh < 2; ++nh) {
    f32x4 acc[4][4];
#pragma unroll
    for (int a = 0; a < 4; ++a)
#pragma unroll
      for (int t = 0; t < 4; ++t) acc[a][t] = (f32x4){0.f, 0.f, 0.f, 0.f};
    for (int kk = 0; kk < HID; kk += 32) {
#pragma unroll
      for (int i = 0; i < 2; ++i) {
        int c = tid + 256 * i; int n = c >> 2, cc = (c & 3) * 8;
        short8 wv = *(const short8*)(Wb + ((size_t)(nh * 128 + n)) * HID + kk + cc);
        *(short8*)&wtile[n * 40 + cc] = wv;
      }
      __syncthreads();
      short8 af[4], bfr[4];
#pragma unroll
      for (int a = 0; a < 4; ++a) af[a]  = *(const short8*)&inb[(wm * 64 + a * 16 + l15) * 264 + kk + lq * 8];
#pragma unroll
      for (int t = 0; t < 4; ++t) bfr[t] = *(const short8*)&wtile[(wn * 64 + t * 16 + l15) * 40 + lq * 8];
#pragma unroll
      for (int a = 0; a < 4; ++a)
#pragma unroll
        for (int t = 0; t < 4; ++t)
          acc[a][t] = __builtin_amdgcn_mfma_f32_16x16x32_bf16(af[a], bfr[t], acc[a][t], 0, 0, 0);
      __syncthreads();
    }
#pragma unroll
    for (int t = 0; t < 4; ++t) {
      int col = nh * 128 + wn * 64 + t * 16 + l15;
      float bv = (EPI < 2) ? bias[col] : 0.f;
#pragma unroll
      for (int a = 0; a < 4; ++a)
#pragma unroll
        for (int r4 = 0; r4 < 4; ++r4) {
          int row = wm * 64 + a * 16 + lq * 4 + r4;
          float v = acc[a][t][r4] + bv;
          if (EPI == 0) { outb[row * 264 + col] = f2bf(fmaxf(v, 0.f)); }
          else if (EPI == 1) { outb[row * 264 + col] = f2bf(tanhf(v)); }
          else { outg[((size_t)(band * 128 + row)) * HID + col] = v; }
        }
    }
  }
  __syncthreads();
}

__global__ __launch_bounds__(256, 1) void fused_kernel(
    const unsigned short* __restrict__ statesb, const float* __restrict__ logsig,
    const unsigned short* __restrict__ W1b, const unsigned short* __restrict__ W2b,
    const unsigned short* __restrict__ W3b, const unsigned short* __restrict__ Wlb,
    const float* __restrict__ b1, const float* __restrict__ b2, const float* __restrict__ b3,
    float* __restrict__ out, FuseArgs F)
{
  __shared__ __align__(16) unsigned short act1[128 * 264];
  __shared__ __align__(16) unsigned short act2[128 * 264];
  __shared__ __align__(16) unsigned short atile[128 * 40];
  __shared__ __align__(16) unsigned short wtile[128 * 40];
  const int tid = threadIdx.x, band = blockIdx.x;
  const int lane = tid & 63, wave = tid >> 6;
  const int wm = wave & 1, wn = wave >> 1;
  const int l15 = lane & 15, lq = lane >> 4;

  for (int nh = 0; nh < 2; ++nh) {
    f32x4 acc[4][4];
#pragma unroll
    for (int a = 0; a < 4; ++a)
#pragma unroll
      for (int t = 0; t < 4; ++t) acc[a][t] = (f32x4){0.f, 0.f, 0.f, 0.f};
    for (int kk = 0; kk < K1P; kk += 32) {
#pragma unroll
      for (int i = 0; i < 2; ++i) {        // stage A-tile 128x32
        int c = tid + 256 * i;
        int r = c >> 2, cc = (c & 3) * 8;
        int col = kk + cc;
        int bA = band * 2 + (r >> 6), ks = r & 63;
        short8 pk;
        if (col < HID) {
          pk = *(const short8*)(statesb + ((size_t)bA * MAXST + F.sidx[ks]) * HID + col);
        } else {
          const float* sp = logsig + ((size_t)bA * WIN + ks) * LSIG + (col - HID);
          float4 v0 = ((const float4*)sp)[0];
          float4 v1 = ((const float4*)sp)[1];
          pk[0] = (short)f2bf(v0.x); pk[1] = (short)f2bf(v0.y); pk[2] = (short)f2bf(v0.z); pk[3] = (short)f2bf(v0.w);
          pk[4] = (short)f2bf(v1.x); pk[5] = (short)f2bf(v1.y); pk[6] = (short)f2bf(v1.z); pk[7] = (short)f2bf(v1.w);
        }
        *(short8*)&atile[r * 40 + cc] = pk;
      }
#pragma unroll
      for (int i = 0; i < 2; ++i) {        // stage W-tile 128x32
        int c = tid + 256 * i; int n = c >> 2, cc = (c & 3) * 8;
        short8 wv = *(const short8*)(W1b + ((size_t)(nh * 128 + n)) * K1P + kk + cc);
        *(short8*)&wtile[n * 40 + cc] = wv;
      }
      __syncthreads();
      short8 af[4], bfr[4];
#pragma unroll
      for (int a = 0; a < 4; ++a) af[a]  = *(const short8*)&atile[(wm * 64 + a * 16 + l15) * 40 + lq * 8];
#pragma unroll
      for (int t = 0; t < 4; ++t) bfr[t] = *(const short8*)&wtile[(wn * 64 + t * 16 + l15) * 40 + lq * 8];
#pragma unroll
      for (int a = 0; a < 4; ++a)
#pragma unroll
        for (int t = 0; t < 4; ++t)
          acc[a][t] = __builtin_amdgcn_mfma_f32_16x16x32_bf16(af[a], bfr[t], acc[a][t], 0, 0, 0);
      __syncthreads();
    }
#pragma unroll
    for (int t = 0; t < 4; ++t) {
      int col = nh * 128 + wn * 64 + t * 16 + l15;
      float bv = b1[col];
#pragma unroll
      for (int a = 0; a < 4; ++a)
#pragma unroll
        for (int r4 = 0; r4 < 4; ++r4) {
          int row = wm * 64 + a * 16 + lq * 4 + r4;
          act1[row * 264 + col] = f2bf(fmaxf(acc[a][t][r4] + bv, 0.f));
        }
    }
  }
  __syncthreads();

  layer_234<0>(act1, act2, W2b, b2, nullptr, band, wtile, tid, wm, wn, l15, lq);
  layer_234<1>(act2, act1, W3b, b3, nullptr, band, wtile, tid, wm, wn, l15, lq);
  layer_234<2>(act1, nullptr, Wlb, nullptr, out, band, wtile, tid, wm, wn, l15, lq);
}

// ---------------------------------------------------------------- host schedule
static void build_sched(SchedArgs& P, CombArgs& CB, ChainArgs& CH, FuseArgs& FU) {
  double tb[SLEN], tt[WIN], tu[NWIN];
  const double s999 = 1.0 / (double)(SLEN - 1);
  const double s63  = 1.0 / (double)(WIN - 1);
  for (int i = 0; i < SLEN; ++i) tb[i] = (double)i * s999;
  tb[SLEN - 1] = 1.0;
  for (int k = 0; k < WIN; ++k) tt[k] = (double)k * s63;
  tt[WIN - 1] = 1.0;
  for (int j = 0; j < NWIN; ++j) tu[j] = tb[50 * j];

  int t_idx[WIN - 1], u_for_t[WIN - 1];
  for (int k = 1; k < WIN; ++k) {
    int ii = 0;
    for (int q = 0; q < SLEN; ++q) if (tb[q] <= tt[k]) ii = q;
    t_idx[k - 1] = ii;
    int jj = 0;
    for (int q = 0; q < NWIN; ++q) if (tu[q] <= tt[k]) jj = q;
    u_for_t[k - 1] = jj;
  }
  for (int t = 0; t < SLEN - 1; ++t) P.snapk[t] = 0;
  for (int m = 1; m < WIN; ++m) P.snapk[t_idx[m - 1] - 1] = (short)m;

  for (int m = 0; m < WIN; ++m) { CB.winofm[m] = 0; CB.zl[m] = 0; }
  for (int m = 1; m < WIN; ++m) {
    int p = t_idx[m - 1];
    CB.winofm[m] = (unsigned char)((p - 1) / 50);
    CB.zl[m] = (p % 50 == 0) ? 1 : 0;
  }

  double qt[32]; int nq = 0, last = -1;
  for (int m = 0; m < WIN - 1; ++m) {
    const int iu = u_for_t[m];
    if (iu != last) { qt[nq++] = tu[iu]; last = iu; }
  }
  qt[nq++] = tt[WIN - 1];
  int upd[WIN]; int qh = 0;
  for (int i = 0; i < WIN; ++i) {
    upd[i] = 0;
    if (qh < nq && tt[i] >= qt[qh]) { qh++; upd[i] = 1; }
  }
  int nU = 0;
  for (int k = 0; k < WIN; ++k) if (upd[k]) { if (nU < 32) CH.kU[nU] = (unsigned char)k; ++nU; }
  int cnt = 0;
  for (int k = 0; k < WIN; ++k) { FU.sidx[k] = (unsigned char)cnt; if (upd[k]) ++cnt; }
  CH.nsteps = FU.sidx[WIN - 1];
}

extern "C" void kernel_launch(void* const* d_in, const int* in_sizes, int n_in,
                              void* d_out, int out_size, void* d_ws, size_t ws_size,
                              hipStream_t stream) {
  const float* z  = (const float*)d_in[0];
  const float* W1 = (const float*)d_in[1];
  const float* b1 = (const float*)d_in[2];
  const float* W2 = (const float*)d_in[3];
  const float* b2 = (const float*)d_in[4];
  const float* W3 = (const float*)d_in[5];
  const float* b3 = (const float*)d_in[6];
  const float* Wl = (const float*)d_in[7];

  char* ws = (char*)d_ws;
  float* logsig = (float*)(ws);                                         // 17.83 MB
  size_t o = (size_t)B_SZ * WIN * LSIG * 4;
  float* dxwin            = (float*)(ws + o); o += (size_t)B_SZ * NWIN * DD * 4;
  unsigned short* statesb = (unsigned short*)(ws + o); o += (size_t)B_SZ * MAXST * HID * 2;
  unsigned short* W1b     = (unsigned short*)(ws + o); o += (size_t)HID * K1P * 2;
  unsigned short* W2b     = (unsigned short*)(ws + o); o += (size_t)HID * HID * 2;
  unsigned short* W3b     = (unsigned short*)(ws + o); o += (size_t)HID * HID * 2;
  unsigned short* Wlb     = (unsigned short*)(ws + o); o += (size_t)HID * HID * 2;
  unsigned short* W1f     = (unsigned short*)(ws + o); o += (size_t)13 * 16 * 64 * 8 * 2;
  unsigned short* W2f     = (unsigned short*)(ws + o); o += (size_t)8 * 16 * 64 * 8 * 2;
  unsigned short* W3f     = (unsigned short*)(ws + o); o += (size_t)8 * 16 * 64 * 8 * 2;

  SchedArgs P; CombArgs CB; ChainArgs CH; FuseArgs FU;
  build_sched(P, CB, CH, FU);

  const int wbf_total = HID * K1P + 3 * HID * HID + 13 * 16 * 64 * 8 + 2 * 8 * 16 * 64 * 8;
  wbf_kernel<<<(wbf_total + 255) / 256, 256, 0, stream>>>(
      W1, W2, W3, Wl, W1b, W2b, W3b, Wlb, W1f, W2f, W3f);
  win_kernel<<<dim3(NWIN, B_SZ), 128, 0, stream>>>(z, logsig, dxwin, P);
  comb_kernel<<<dim3(WIN, B_SZ), 128, 0, stream>>>(logsig, dxwin, CB);
  chain_kernel<<<32, 512, 0, stream>>>(logsig, W1f, W2f, W3f, b1, b2, b3, statesb, CH);
  fused_kernel<<<256, 256, 0, stream>>>(statesb, logsig, W1b, W2b, W3b, Wlb,
                                        b1, b2, b3, (float*)d_out, FU);
}

// Round 9
// 312.372 us; speedup vs baseline: 1.1772x; 1.1286x over previous
//
#include <hip/hip_runtime.h>
#include <hip/hip_bf16.h>
#include <cmath>
#include <cstring>

#define B_SZ   512
#define SLEN   1000
#define DD     16
#define HID    256
#define WIN    64
#define PAIRS  120
#define LSIG   136
#define NWIN   20
#define MAXST  21
#define K1P    416     // layer-1 K padded to x32
#define W1FN   (13 * 16 * 64 * 8)   // 106496 elems
#define WFN    (8 * 16 * 64 * 8)    // 65536 elems (W2/W3/Wl)

using short8 = __attribute__((ext_vector_type(8))) short;
using half8  = __attribute__((ext_vector_type(8))) _Float16;
using f32x4  = __attribute__((ext_vector_type(4))) float;

struct SchedArgs { short snapk[SLEN - 1]; };
struct CombArgs  { unsigned char winofm[WIN]; unsigned char zl[WIN]; };
struct ChainArgs { int nsteps; unsigned char kU[32]; };
struct FuseArgs  { unsigned char sidx[WIN]; };

__device__ __forceinline__ unsigned short f2h(float x) {
  _Float16 h = (_Float16)x;
  return __builtin_bit_cast(unsigned short, h);
}
__device__ __forceinline__ float ftanh(float x) {   // clamped; |err|~1e-6
  float t = fminf(fmaxf(2.f * x, -30.f), 30.f);
  float e = __expf(t);
  return (e - 1.f) / (e + 1.f);
}

// ---------------------------------------------------------------- prep: win scan + weight frag convert
// grid (NWIN+3, B_SZ) x 128. Blocks w<NWIN: per-window Levy scan. Else: convert
// W1/W2/W3/Wl -> fp16 MFMA B-frag layout:
//   Wf[(kk*16+nsub)*64+lane][j] = W[nsub*16+(lane&15)][kk*32+(lane>>4)*8+j]
__global__ __launch_bounds__(128) void prep_kernel(
    const float* __restrict__ z,
    const float* __restrict__ W1, const float* __restrict__ W2,
    const float* __restrict__ W3, const float* __restrict__ Wl,
    float* __restrict__ logsig, float* __restrict__ dxwin,
    unsigned short* __restrict__ W1f, unsigned short* __restrict__ W2f,
    unsigned short* __restrict__ W3f, unsigned short* __restrict__ Wlf,
    SchedArgs A)
{
  const int w = blockIdx.x, b = blockIdx.y, tid = threadIdx.x;
  if (w >= NWIN) {                                   // ---- weight conversion
    const int slot = ((w - NWIN) * B_SZ + b) * 128 + tid;   // 196608 slots
    for (int e = slot; e < W1FN + 3 * WFN; e += 3 * B_SZ * 128) {
      if (e < W1FN) {
        int f = e;
        int j = f & 7, l15 = (f >> 3) & 15, lq = (f >> 7) & 3, nsub = (f >> 9) & 15, kk = f >> 13;
        int row = nsub * 16 + l15, col = kk * 32 + lq * 8 + j;
        float v = (col < HID + LSIG) ? W1[(size_t)row * (HID + LSIG) + col] : 0.f;
        W1f[f] = f2h(v);
      } else {
        int e2 = e - W1FN;
        int which = e2 >> 16, f = e2 & 65535;
        int j = f & 7, l15 = (f >> 3) & 15, lq = (f >> 7) & 3, nsub = (f >> 9) & 15, kk = (f >> 13) & 7;
        int row = nsub * 16 + l15, col = kk * 32 + lq * 8 + j;
        const float* src = which == 0 ? W2 : which == 1 ? W3 : Wl;
        unsigned short* dst = which == 0 ? W2f : which == 1 ? W3f : Wlf;
        dst[f] = f2h(src[(size_t)row * HID + col]);
      }
    }
    return;
  }
  // ---- per-window Levy scan (dtsqrt inlined)
  __shared__ float zs[50][16];
  const int ns = (w == NWIN - 1) ? 49 : 50;
  const float* src = z + ((size_t)b * SLEN + 50 * w + 1) * DD;
  const double s999 = 1.0 / (double)(SLEN - 1);
  for (int c = tid; c < ns * 4; c += 128) {
    float4 v = ((const float4*)src)[c];
    int t = 50 * w + (c >> 2);
    double a = (t + 1 == SLEN - 1) ? 1.0 : (double)(t + 1) * s999;
    float s = sqrtf((float)(a - (double)t * s999));
    v.x *= s; v.y *= s; v.z *= s; v.w *= s;
    ((float4*)&zs[0][0])[c] = v;
  }
  int pi = 0, pj = 0;
  if (tid < PAIRS) { int rem = tid, i = 0; while (rem >= DD - 1 - i) { rem -= DD - 1 - i; ++i; } pi = i; pj = i + 1 + rem; }
  __syncthreads();
  float Yi = 0.f, Yj = 0.f, LL = 0.f, Yd = 0.f;
  const int base_t = 50 * w;
  for (int u = 0; u < ns; ++u) {
    const float di = zs[u][pi], dj = zs[u][pj];
    LL = fmaf(Yi, dj, LL); LL = fmaf(-Yj, di, LL);
    Yi += di; Yj += dj;
    if (tid < DD) Yd += zs[u][tid];
    const int m = A.snapk[base_t + u];
    if (m) {
      float* dst = logsig + ((size_t)b * WIN + m) * LSIG;
      if (tid < DD)    dst[tid]      = Yd;
      if (tid < PAIRS) dst[DD + tid] = LL;
    }
  }
  if (tid < DD) dxwin[((size_t)b * NWIN + w) * DD + tid] = Yd;
}

// ---------------------------------------------------------------- combine windows (fully parallel)
__global__ __launch_bounds__(128) void comb_kernel(
    float* __restrict__ logsig, const float* __restrict__ dxwin, CombArgs A)
{
  const int m = blockIdx.x, b = blockIdx.y, tid = threadIdx.x;
  float* row = logsig + ((size_t)b * WIN + m) * LSIG;
  if (m == 0) {
    if (tid < LSIG) row[tid] = 0.f;
    if (tid + 128 < LSIG) row[tid + 128] = 0.f;
    return;
  }
  __shared__ float Xs[DD], Yt[DD];
  const int w = A.winofm[m];
  if (tid < DD) {
    float acc = 0.f;
    for (int ww = 0; ww < w; ++ww) acc += dxwin[((size_t)b * NWIN + ww) * DD + tid];
    float y = row[tid];
    Xs[tid] = acc; Yt[tid] = y;
    row[tid] = acc + y;
  }
  __syncthreads();
  if (tid < PAIRS) {
    int rem = tid, i = 0; while (rem >= DD - 1 - i) { rem -= DD - 1 - i; ++i; }
    const int pi = i, pj = i + 1 + rem;
    float ll = row[DD + tid];
    row[DD + tid] = A.zl[m] ? 0.f : 0.5f * (ll + Xs[pi] * Yt[pj] - Xs[pj] * Yt[pi]);
  }
}

// ---------------------------------------------------------------- sequential state chain (fp16 MFMA)
// 32 blocks x 512 thr (8 waves). M=16 rows/block; wave w owns cols [32w,32w+32).
// NO weight registers (compiler caps 512-thr blocks at 128 VGPR -> R6/7/8 all
// spilled; reg-resident weights reload from scratch every step). W2 frags in
// LDS (128KB, loaded once); W1 (26 frags) + W3 (16 frags) streamed per step
// with a zoff*m term (zoff==0 at runtime) so LICM cannot hoist them into regs.
// Chunk-of-8 activation layout -> conflict-free ds_read_b128. 3 barriers/step.
__global__ __launch_bounds__(512, 1) void chain_kernel(
    const float* __restrict__ logsig,
    const unsigned short* __restrict__ W1f, const unsigned short* __restrict__ W2f,
    const unsigned short* __restrict__ W3f,
    const float* __restrict__ b1, const float* __restrict__ b2, const float* __restrict__ b3,
    unsigned short* __restrict__ statesb, ChainArgs A, int zoff)
{
  __shared__ __align__(16) unsigned short A0s[52 * 16 * 8];   // 13.0 KB
  __shared__ __align__(16) unsigned short A1s[32 * 16 * 8];   //  8 KB
  __shared__ __align__(16) unsigned short A2s[32 * 16 * 8];   //  8 KB
  __shared__ __align__(16) unsigned short W2L[WFN];           // 128 KB
  const int tid = threadIdx.x, g = blockIdx.x;
  const int lane = tid & 63, w = tid >> 6;
  const int l15 = lane & 15, lq = lane >> 4;

  for (int c = tid; c < 52 * 16 * 8; c += 512) A0s[c] = 0;
  for (int c = tid; c < 16 * HID; c += 512) {
    int r = c >> 8, col = c & 255;
    statesb[((size_t)(g * 16 + r) * MAXST + 0) * HID + col] = 0;
  }
  for (int c = tid; c < WFN / 8; c += 512)            // W2 frags -> LDS (once)
    *(short8*)&W2L[c * 8] = *(const short8*)(W2f + (size_t)c * 8);

  float bias1[2], bias2[2], bias3[2];
#pragma unroll
  for (int nt = 0; nt < 2; ++nt) {
    int col = (w * 2 + nt) * 16 + l15;
    bias1[nt] = b1[col]; bias2[nt] = b2[col]; bias3[nt] = b3[col];
  }
  // logsig staging plumbing (chunk-of-8 target region, cols 256..391)
  int gofs[5]; int a0off[5]; int nld = 0;
#pragma unroll
  for (int i = 0; i < 5; ++i) {
    int c = tid + 512 * i;
    if (c < 16 * LSIG) {
      int r = c / LSIG, cc = c - r * LSIG;
      gofs[i] = ((g * 16 + r) * WIN) * LSIG + cc;
      a0off[i] = (((HID + cc) >> 3) * 16 + r) * 8 + ((HID + cc) & 7);
      nld = i + 1;
    }
  }
  float lsr[5];
  {
    const int k0 = A.kU[0];
    for (int i = 0; i < nld; ++i) lsr[i] = logsig[gofs[i] + k0 * LSIG];
  }
  __syncthreads();
  for (int i = 0; i < nld; ++i) A0s[a0off[i]] = f2h(lsr[i]);
  __syncthreads();

  for (int m = 0; m < A.nsteps; ++m) {
    const unsigned short* w1m = W1f + (size_t)zoff * m;   // defeats hoisting
    const unsigned short* w3m = W3f + (size_t)zoff * m;
    if (m + 1 < A.nsteps) {
      const int kn = A.kU[m + 1];
      for (int i = 0; i < nld; ++i) lsr[i] = logsig[gofs[i] + kn * LSIG];
    }
    // ---- L1: K=416, W1 frags streamed from L2
    {
      f32x4 acc[2][2] = {{{0.f,0.f,0.f,0.f},{0.f,0.f,0.f,0.f}},{{0.f,0.f,0.f,0.f},{0.f,0.f,0.f,0.f}}};
#pragma unroll
      for (int kk = 0; kk < 13; ++kk) {
        half8 af = *(const half8*)&A0s[((kk * 4 + lq) * 16 + l15) * 8];
        half8 bf0 = *(const half8*)(w1m + ((size_t)(kk * 16 + w * 2    ) * 64 + lane) * 8);
        half8 bf1 = *(const half8*)(w1m + ((size_t)(kk * 16 + w * 2 + 1) * 64 + lane) * 8);
        acc[kk & 1][0] = __builtin_amdgcn_mfma_f32_16x16x32_f16(af, bf0, acc[kk & 1][0], 0, 0, 0);
        acc[kk & 1][1] = __builtin_amdgcn_mfma_f32_16x16x32_f16(af, bf1, acc[kk & 1][1], 0, 0, 0);
      }
#pragma unroll
      for (int nt = 0; nt < 2; ++nt) {
        f32x4 s = acc[0][nt] + acc[1][nt];
        int col = w * 32 + nt * 16 + l15;
        int base = ((col >> 3) * 16) * 8 + (col & 7);
#pragma unroll
        for (int r4 = 0; r4 < 4; ++r4)
          A1s[base + (lq * 4 + r4) * 8] = f2h(fmaxf(s[r4] + bias1[nt], 0.f));
      }
    }
    __syncthreads();
    if (m + 1 < A.nsteps)                       // stage logsig(m+1): visible after L3 barrier
      for (int i = 0; i < nld; ++i) A0s[a0off[i]] = f2h(lsr[i]);
    // ---- L2: K=256, W2 frags from LDS
    {
      f32x4 acc[2][2] = {{{0.f,0.f,0.f,0.f},{0.f,0.f,0.f,0.f}},{{0.f,0.f,0.f,0.f},{0.f,0.f,0.f,0.f}}};
#pragma unroll
      for (int kk = 0; kk < 8; ++kk) {
        half8 af = *(const half8*)&A1s[((kk * 4 + lq) * 16 + l15) * 8];
        half8 bf0 = *(const half8*)&W2L[((kk * 16 + w * 2    ) * 64 + lane) * 8];
        half8 bf1 = *(const half8*)&W2L[((kk * 16 + w * 2 + 1) * 64 + lane) * 8];
        acc[kk & 1][0] = __builtin_amdgcn_mfma_f32_16x16x32_f16(af, bf0, acc[kk & 1][0], 0, 0, 0);
        acc[kk & 1][1] = __builtin_amdgcn_mfma_f32_16x16x32_f16(af, bf1, acc[kk & 1][1], 0, 0, 0);
      }
#pragma unroll
      for (int nt = 0; nt < 2; ++nt) {
        f32x4 s = acc[0][nt] + acc[1][nt];
        int col = w * 32 + nt * 16 + l15;
        int base = ((col >> 3) * 16) * 8 + (col & 7);
#pragma unroll
        for (int r4 = 0; r4 < 4; ++r4)
          A2s[base + (lq * 4 + r4) * 8] = f2h(fmaxf(s[r4] + bias2[nt], 0.f));
      }
    }
    __syncthreads();
    // ---- L3: K=256, W3 streamed; fast tanh -> A0 state + export fp16
    {
      f32x4 acc[2][2] = {{{0.f,0.f,0.f,0.f},{0.f,0.f,0.f,0.f}},{{0.f,0.f,0.f,0.f},{0.f,0.f,0.f,0.f}}};
#pragma unroll
      for (int kk = 0; kk < 8; ++kk) {
        half8 af = *(const half8*)&A2s[((kk * 4 + lq) * 16 + l15) * 8];
        half8 bf0 = *(const half8*)(w3m + ((size_t)(kk * 16 + w * 2    ) * 64 + lane) * 8);
        half8 bf1 = *(const half8*)(w3m + ((size_t)(kk * 16 + w * 2 + 1) * 64 + lane) * 8);
        acc[kk & 1][0] = __builtin_amdgcn_mfma_f32_16x16x32_f16(af, bf0, acc[kk & 1][0], 0, 0, 0);
        acc[kk & 1][1] = __builtin_amdgcn_mfma_f32_16x16x32_f16(af, bf1, acc[kk & 1][1], 0, 0, 0);
      }
#pragma unroll
      for (int nt = 0; nt < 2; ++nt) {
        f32x4 s = acc[0][nt] + acc[1][nt];
        int col = w * 32 + nt * 16 + l15;
        int base = ((col >> 3) * 16) * 8 + (col & 7);
#pragma unroll
        for (int r4 = 0; r4 < 4; ++r4) {
          int row = lq * 4 + r4;
          float tv = ftanh(s[r4] + bias3[nt]);
          unsigned short hv = f2h(tv);
          A0s[base + row * 8] = hv;
          statesb[((size_t)(g * 16 + row) * MAXST + (m + 1)) * HID + col] = hv;
        }
      }
    }
    __syncthreads();
  }
}

// ---------------------------------------------------------------- fused batched MLP (fp16 MFMA)
// 256 blocks x 256 thr (4 waves, 1 wave/SIMD -> full VGPR headroom). 128 rows
// (2 batch rows x 64 steps) x all 4 layers. Wave w owns n-tiles w*4..w*4+3
// (64 cols) x all 8 m-tiles -> acc[8][4], no duplicate B reads across waves.
// B-frags straight from L2 (pre-fragmented, 1KB/inst, each read once/block).
// Acts in chunk-of-8 LDS (conflict-free). Barriers: 13 (L1 A-staging, double-
// buffered) + 3 inter-layer  (was ~148).
__global__ __launch_bounds__(256, 1) void fused_kernel(
    const unsigned short* __restrict__ statesb, const float* __restrict__ logsig,
    const unsigned short* __restrict__ W1f, const unsigned short* __restrict__ W2f,
    const unsigned short* __restrict__ W3f, const unsigned short* __restrict__ Wlf,
    const float* __restrict__ b1, const float* __restrict__ b2, const float* __restrict__ b3,
    float* __restrict__ out, FuseArgs F)
{
  __shared__ __align__(16) unsigned short act1[32 * 128 * 8];   // 64 KB, chunk-8 [col>>3][row][col&7]
  __shared__ __align__(16) unsigned short act2[32 * 128 * 8];   // 64 KB
  __shared__ __align__(16) unsigned short atile[2][4 * 128 * 8];// 2 x 8 KB
  const int tid = threadIdx.x, band = blockIdx.x;
  const int lane = tid & 63, w = tid >> 6;
  const int l15 = lane & 15, lq = lane >> 4;

  float bias1[4], bias2[4], bias3[4];
#pragma unroll
  for (int t = 0; t < 4; ++t) {
    int col = w * 64 + t * 16 + l15;
    bias1[t] = b1[col]; bias2[t] = b2[col]; bias3[t] = b3[col];
  }

  // ---- L1: K=416, A staged per-kk (dbuf), B-frags from L2
  f32x4 acc[8][4];
#pragma unroll
  for (int a = 0; a < 8; ++a)
#pragma unroll
    for (int t = 0; t < 4; ++t) acc[a][t] = (f32x4){0.f, 0.f, 0.f, 0.f};

  short8 pk[2];
  auto loadA = [&](int kk, short8* p) {
#pragma unroll
    for (int i = 0; i < 2; ++i) {
      int c = tid + 256 * i;
      int r = c >> 2, cc = (c & 3) * 8;
      int col = kk * 32 + cc;
      int bA = band * 2 + (r >> 6), ks = r & 63;
      if (col < HID) {
        p[i] = *(const short8*)(statesb + ((size_t)bA * MAXST + F.sidx[ks]) * HID + col);
      } else {
        const float* sp = logsig + ((size_t)bA * WIN + ks) * LSIG + (col - HID); // tail reads past 136 benign (W pad=0)
        float4 v0 = ((const float4*)sp)[0];
        float4 v1 = ((const float4*)sp)[1];
        short8 q;
        q[0] = (short)f2h(v0.x); q[1] = (short)f2h(v0.y); q[2] = (short)f2h(v0.z); q[3] = (short)f2h(v0.w);
        q[4] = (short)f2h(v1.x); q[5] = (short)f2h(v1.y); q[6] = (short)f2h(v1.z); q[7] = (short)f2h(v1.w);
        p[i] = q;
      }
    }
  };
  loadA(0, pk);
  for (int kk = 0; kk < 13; ++kk) {
    unsigned short* buf = atile[kk & 1];
#pragma unroll
    for (int i = 0; i < 2; ++i) {
      int c = tid + 256 * i;
      int r = c >> 2, ch = c & 3;
      *(short8*)&buf[(ch * 128 + r) * 8] = pk[i];
    }
    __syncthreads();
    if (kk + 1 < 13) loadA(kk + 1, pk);       // issue early; hides under MFMAs
    half8 bfr[4];
#pragma unroll
    for (int t = 0; t < 4; ++t)
      bfr[t] = *(const half8*)(W1f + ((size_t)(kk * 16 + w * 4 + t) * 64 + lane) * 8);
#pragma unroll
    for (int a = 0; a < 8; ++a) {
      half8 af = *(const half8*)&buf[(lq * 128 + a * 16 + l15) * 8];
#pragma unroll
      for (int t = 0; t < 4; ++t)
        acc[a][t] = __builtin_amdgcn_mfma_f32_16x16x32_f16(af, bfr[t], acc[a][t], 0, 0, 0);
    }
    __syncthreads();
  }
#pragma unroll
  for (int a = 0; a < 8; ++a)
#pragma unroll
    for (int t = 0; t < 4; ++t) {
      int col = w * 64 + t * 16 + l15;
      int base = ((col >> 3) * 128) * 8 + (col & 7);
#pragma unroll
      for (int r4 = 0; r4 < 4; ++r4) {
        int row = a * 16 + lq * 4 + r4;
        act1[base + row * 8] = f2h(fmaxf(acc[a][t][r4] + bias1[t], 0.f));
      }
    }
  __syncthreads();

  // ---- generic K=256 layer: A from act LDS, B-frags from L2
  auto layer = [&](const unsigned short* inb, const unsigned short* Wf) {
#pragma unroll
    for (int a = 0; a < 8; ++a)
#pragma unroll
      for (int t = 0; t < 4; ++t) acc[a][t] = (f32x4){0.f, 0.f, 0.f, 0.f};
    for (int kk = 0; kk < 8; ++kk) {
      half8 bfr[4];
#pragma unroll
      for (int t = 0; t < 4; ++t)
        bfr[t] = *(const half8*)(Wf + ((size_t)(kk * 16 + w * 4 + t) * 64 + lane) * 8);
#pragma unroll
      for (int a = 0; a < 8; ++a) {
        half8 af = *(const half8*)&inb[((kk * 4 + lq) * 128 + a * 16 + l15) * 8];
#pragma unroll
        for (int t = 0; t < 4; ++t)
          acc[a][t] = __builtin_amdgcn_mfma_f32_16x16x32_f16(af, bfr[t], acc[a][t], 0, 0, 0);
      }
    }
  };

  layer(act1, W2f);                                   // L2 -> relu -> act2
#pragma unroll
  for (int a = 0; a < 8; ++a)
#pragma unroll
    for (int t = 0; t < 4; ++t) {
      int col = w * 64 + t * 16 + l15;
      int base = ((col >> 3) * 128) * 8 + (col & 7);
#pragma unroll
      for (int r4 = 0; r4 < 4; ++r4) {
        int row = a * 16 + lq * 4 + r4;
        act2[base + row * 8] = f2h(fmaxf(acc[a][t][r4] + bias2[t], 0.f));
      }
    }
  __syncthreads();

  layer(act2, W3f);                                   // L3 -> tanh -> act1
#pragma unroll
  for (int a = 0; a < 8; ++a)
#pragma unroll
    for (int t = 0; t < 4; ++t) {
      int col = w * 64 + t * 16 + l15;
      int base = ((col >> 3) * 128) * 8 + (col & 7);
#pragma unroll
      for (int r4 = 0; r4 < 4; ++r4) {
        int row = a * 16 + lq * 4 + r4;
        act1[base + row * 8] = f2h(ftanh(acc[a][t][r4] + bias3[t]));
      }
    }
  __syncthreads();

  layer(act1, Wlf);                                   // L4 -> fp32 out
#pragma unroll
  for (int a = 0; a < 8; ++a)
#pragma unroll
    for (int t = 0; t < 4; ++t) {
      int col = w * 64 + t * 16 + l15;
#pragma unroll
      for (int r4 = 0; r4 < 4; ++r4) {
        int row = a * 16 + lq * 4 + r4;
        out[((size_t)(band * 128 + row)) * HID + col] = acc[a][t][r4];
      }
    }
}

// ---------------------------------------------------------------- host schedule
static void build_sched(SchedArgs& P, CombArgs& CB, ChainArgs& CH, FuseArgs& FU) {
  double tb[SLEN], tt[WIN], tu[NWIN];
  const double s999 = 1.0 / (double)(SLEN - 1);
  const double s63  = 1.0 / (double)(WIN - 1);
  for (int i = 0; i < SLEN; ++i) tb[i] = (double)i * s999;
  tb[SLEN - 1] = 1.0;
  for (int k = 0; k < WIN; ++k) tt[k] = (double)k * s63;
  tt[WIN - 1] = 1.0;
  for (int j = 0; j < NWIN; ++j) tu[j] = tb[50 * j];

  int t_idx[WIN - 1], u_for_t[WIN - 1];
  for (int k = 1; k < WIN; ++k) {
    int ii = 0;
    for (int q = 0; q < SLEN; ++q) if (tb[q] <= tt[k]) ii = q;
    t_idx[k - 1] = ii;
    int jj = 0;
    for (int q = 0; q < NWIN; ++q) if (tu[q] <= tt[k]) jj = q;
    u_for_t[k - 1] = jj;
  }
  for (int t = 0; t < SLEN - 1; ++t) P.snapk[t] = 0;
  for (int m = 1; m < WIN; ++m) P.snapk[t_idx[m - 1] - 1] = (short)m;

  for (int m = 0; m < WIN; ++m) { CB.winofm[m] = 0; CB.zl[m] = 0; }
  for (int m = 1; m < WIN; ++m) {
    int p = t_idx[m - 1];
    CB.winofm[m] = (unsigned char)((p - 1) / 50);
    CB.zl[m] = (p % 50 == 0) ? 1 : 0;
  }

  double qt[32]; int nq = 0, last = -1;
  for (int m = 0; m < WIN - 1; ++m) {
    const int iu = u_for_t[m];
    if (iu != last) { qt[nq++] = tu[iu]; last = iu; }
  }
  qt[nq++] = tt[WIN - 1];
  int upd[WIN]; int qh = 0;
  for (int i = 0; i < WIN; ++i) {
    upd[i] = 0;
    if (qh < nq && tt[i] >= qt[qh]) { qh++; upd[i] = 1; }
  }
  int nU = 0;
  for (int k = 0; k < WIN; ++k) if (upd[k]) { if (nU < 32) CH.kU[nU] = (unsigned char)k; ++nU; }
  int cnt = 0;
  for (int k = 0; k < WIN; ++k) { FU.sidx[k] = (unsigned char)cnt; if (upd[k]) ++cnt; }
  CH.nsteps = FU.sidx[WIN - 1];
}

extern "C" void kernel_launch(void* const* d_in, const int* in_sizes, int n_in,
                              void* d_out, int out_size, void* d_ws, size_t ws_size,
                              hipStream_t stream) {
  const float* z  = (const float*)d_in[0];
  const float* W1 = (const float*)d_in[1];
  const float* b1 = (const float*)d_in[2];
  const float* W2 = (const float*)d_in[3];
  const float* b2 = (const float*)d_in[4];
  const float* W3 = (const float*)d_in[5];
  const float* b3 = (const float*)d_in[6];
  const float* Wl = (const float*)d_in[7];

  char* ws = (char*)d_ws;
  float* logsig = (float*)(ws);                                         // 17.83 MB
  size_t o = (size_t)B_SZ * WIN * LSIG * 4;
  float* dxwin            = (float*)(ws + o); o += (size_t)B_SZ * NWIN * DD * 4;
  unsigned short* statesb = (unsigned short*)(ws + o); o += (size_t)B_SZ * MAXST * HID * 2;
  unsigned short* W1f     = (unsigned short*)(ws + o); o += (size_t)W1FN * 2;
  unsigned short* W2f     = (unsigned short*)(ws + o); o += (size_t)WFN * 2;
  unsigned short* W3f     = (unsigned short*)(ws + o); o += (size_t)WFN * 2;
  unsigned short* Wlf     = (unsigned short*)(ws + o); o += (size_t)WFN * 2;

  SchedArgs P; CombArgs CB; ChainArgs CH; FuseArgs FU;
  build_sched(P, CB, CH, FU);

  prep_kernel<<<dim3(NWIN + 3, B_SZ), 128, 0, stream>>>(
      z, W1, W2, W3, Wl, logsig, dxwin, W1f, W2f, W3f, Wlf, P);
  comb_kernel<<<dim3(WIN, B_SZ), 128, 0, stream>>>(logsig, dxwin, CB);
  chain_kernel<<<32, 512, 0, stream>>>(logsig, W1f, W2f, W3f, b1, b2, b3, statesb, CH, 0);
  fused_kernel<<<256, 256, 0, stream>>>(statesb, logsig, W1f, W2f, W3f, Wlf,
                                        b1, b2, b3, (float*)d_out, FU);
}